// Round 14
// baseline (215.711 us; speedup 1.0000x reference)
//
#include <hip/hip_runtime.h>
#include <math.h>

#define BATCH  4
#define SEQL   2048
#define BLROWS (BATCH*SEQL)     // 8192
#define DMODEL 256
#define DINNER 512
#define DSTATE 16
#define DTRANK 16
#define NCHUNK 128
#define CHLEN  (SEQL/NCHUNK)    // 16

typedef __attribute__((ext_vector_type(8))) __bf16 bf16x8;
typedef __attribute__((ext_vector_type(4))) float f32x4;
typedef unsigned short ushort_t;

__device__ __forceinline__ float sigmoidf_(float x) { return 1.f/(1.f+__expf(-x)); }
__device__ __forceinline__ float siluf_(float x)    { return x*sigmoidf_(x); }
__device__ __forceinline__ float softplusf_(float x){
  float e = __expf(-fabsf(x));
  return fmaxf(x, 0.f) + __logf(1.f + e);
}
__device__ __forceinline__ float geluf_(float x){
  const float c = 0.7978845608028654f;
  float t = c*(x + 0.044715f*x*x*x);
  float e = __expf(2.f*t);
  float th = 1.f - 2.f/(e + 1.f);
  return 0.5f*x*(1.f+th);
}
__device__ __forceinline__ ushort_t f2bf(float f){
  unsigned int u = __float_as_uint(f);
  u = (u + 0x7FFFu + ((u>>16)&1u)) >> 16;
  return (ushort_t)u;
}
__device__ __forceinline__ float bf2f(ushort_t b){
  return __uint_as_float(((unsigned int)b) << 16);
}
// p[n] = r^(n+1), tree depth ~4
__device__ __forceinline__ void pow16_(float r, float* p){
  float r2 = r*r, r4 = r2*r2, r8 = r4*r4;
  p[0]=r;      p[1]=r2;     p[2]=r2*r;   p[3]=r4;
  p[4]=r4*r;   p[5]=r4*r2;  p[6]=r4*p[2];p[7]=r8;
  p[8]=r8*r;   p[9]=r8*r2;  p[10]=r8*p[2];p[11]=r8*r4;
  p[12]=r8*p[4];p[13]=r8*p[5];p[14]=r8*p[6];p[15]=r8*r8;
}

enum { EPI_NONE=0, EPI_BIAS_BF=1, EPI_GELU_ADD_BF=3, EPI_XZ=4 };

// ---------------- bf16 MFMA GEMM, BM=128 BN=128 BK=32 (round-12 known-good) ----------------
template<int EPI>
__global__ __launch_bounds__(256) void bgemm128(
    const ushort_t* __restrict__ A, const ushort_t* __restrict__ W,
    const float* __restrict__ bias, const void* __restrict__ Rv,
    void* __restrict__ Cv, int M, int N, int K)
{
  __shared__ __align__(16) char smA[8192];
  __shared__ __align__(16) char smW[8192];
  float* Cf = (float*)Cv;
  ushort_t* Cb = (ushort_t*)Cv;
  const ushort_t* Rb = (const ushort_t*)Rv;
  const int tid  = threadIdx.x;
  const int w    = tid >> 6;
  const int lane = tid & 63;
  const int lr = lane & 15, lh = lane >> 4;
  const int wr = w >> 1, wc = w & 1;
  const int bm = blockIdx.x * 128, bn = blockIdx.y * 128;

  const int srow  = tid >> 2;
  const int sslot = tid & 3;
  const int lslot = sslot ^ ((srow >> 1) & 3);
  const size_t aoff0 = (size_t)(bm + srow)      * K + lslot*8;
  const size_t aoff1 = (size_t)(bm + srow + 64) * K + lslot*8;
  const int wrow0 = bn + srow, wrow1 = bn + srow + 64;
  const size_t woff0 = (size_t)wrow0 * K + lslot*8;
  const size_t woff1 = (size_t)wrow1 * K + lslot*8;

  f32x4 acc[4][4];
  #pragma unroll
  for (int m=0;m<4;m++)
    #pragma unroll
    for (int n=0;n<4;n++) acc[m][n] = (f32x4){0.f,0.f,0.f,0.f};

  int4 ar0, ar1, br0, br1;
  const int4 z4 = make_int4(0,0,0,0);
  ar0 = *(const int4*)(A + aoff0);
  ar1 = *(const int4*)(A + aoff1);
  br0 = (wrow0 < N) ? *(const int4*)(W + woff0) : z4;
  br1 = (wrow1 < N) ? *(const int4*)(W + woff1) : z4;

  for (int k0 = 0; k0 < K; k0 += 32) {
    __syncthreads();
    *(int4*)(smA +        tid*16) = ar0;
    *(int4*)(smA + 4096 + tid*16) = ar1;
    *(int4*)(smW +        tid*16) = br0;
    *(int4*)(smW + 4096 + tid*16) = br1;
    __syncthreads();
    if (k0 + 32 < K) {
      int k1 = k0 + 32;
      ar0 = *(const int4*)(A + aoff0 + k1);
      ar1 = *(const int4*)(A + aoff1 + k1);
      br0 = (wrow0 < N) ? *(const int4*)(W + woff0 + k1) : z4;
      br1 = (wrow1 < N) ? *(const int4*)(W + woff1 + k1) : z4;
    }
    bf16x8 af[4], bfr[4];
    #pragma unroll
    for (int m=0;m<4;m++) {
      int r = wr*64 + m*16 + lr;
      af[m] = *(const bf16x8*)(smA + r*64 + ((lh ^ ((r>>1)&3))<<4));
    }
    #pragma unroll
    for (int n=0;n<4;n++) {
      int r = wc*64 + n*16 + lr;
      bfr[n] = *(const bf16x8*)(smW + r*64 + ((lh ^ ((r>>1)&3))<<4));
    }
    #pragma unroll
    for (int m=0;m<4;m++)
      #pragma unroll
      for (int n=0;n<4;n++)
        acc[m][n] = __builtin_amdgcn_mfma_f32_16x16x32_bf16(af[m], bfr[n], acc[m][n], 0,0,0);
  }

  #pragma unroll
  for (int m=0;m<4;m++) {
    #pragma unroll
    for (int n=0;n<4;n++) {
      int col = bn + wc*64 + n*16 + lr;
      if (col >= N) continue;
      #pragma unroll
      for (int j=0;j<4;j++) {
        int row = bm + wr*64 + m*16 + lh*4 + j;
        float v = acc[m][n][j];
        size_t idx = (size_t)row*N + col;
        if      (EPI == EPI_BIAS_BF)     Cb[idx] = f2bf(v + bias[col]);
        else if (EPI == EPI_GELU_ADD_BF) Cb[idx] = f2bf(geluf_(v) + bf2f(Rb[idx]));
        else if (EPI == EPI_XZ)          Cb[idx] = f2bf(v);
        else                             Cf[idx] = v;
      }
    }
  }
}

// ---------------- bf16 MFMA GEMM, BM=64 BN=128 BK=32 (round-12 known-good) ----------------
template<int EPI>
__global__ __launch_bounds__(256) void bgemm64(
    const ushort_t* __restrict__ A, const ushort_t* __restrict__ W,
    const float* __restrict__ bias, const void* __restrict__ Rv,
    void* __restrict__ Cv, int M, int N, int K)
{
  __shared__ __align__(16) char smA[4096];
  __shared__ __align__(16) char smW[8192];
  float* Cf = (float*)Cv;
  ushort_t* Cb = (ushort_t*)Cv;
  const ushort_t* Rb = (const ushort_t*)Rv;
  const int tid  = threadIdx.x;
  const int w    = tid >> 6;
  const int lane = tid & 63;
  const int lr = lane & 15, lh = lane >> 4;
  const int wr = w >> 1, wc = w & 1;
  const int bm = blockIdx.x * 64, bn = blockIdx.y * 128;

  const int srow  = tid >> 2;
  const int sslot = tid & 3;
  const int lslot = sslot ^ ((srow >> 1) & 3);
  const size_t aoff  = (size_t)(bm + srow) * K + lslot*8;
  const int wrow0 = bn + srow, wrow1 = bn + srow + 64;
  const size_t woff0 = (size_t)wrow0 * K + lslot*8;
  const size_t woff1 = (size_t)wrow1 * K + lslot*8;

  f32x4 acc[2][4];
  #pragma unroll
  for (int m=0;m<2;m++)
    #pragma unroll
    for (int n=0;n<4;n++) acc[m][n] = (f32x4){0.f,0.f,0.f,0.f};

  int4 ar, br0, br1;
  const int4 z4 = make_int4(0,0,0,0);
  ar  = *(const int4*)(A + aoff);
  br0 = (wrow0 < N) ? *(const int4*)(W + woff0) : z4;
  br1 = (wrow1 < N) ? *(const int4*)(W + woff1) : z4;

  for (int k0 = 0; k0 < K; k0 += 32) {
    __syncthreads();
    *(int4*)(smA + tid*16)        = ar;
    *(int4*)(smW + tid*16)        = br0;
    *(int4*)(smW + 4096 + tid*16) = br1;
    __syncthreads();
    if (k0 + 32 < K) {
      int k1 = k0 + 32;
      ar  = *(const int4*)(A + aoff + k1);
      br0 = (wrow0 < N) ? *(const int4*)(W + woff0 + k1) : z4;
      br1 = (wrow1 < N) ? *(const int4*)(W + woff1 + k1) : z4;
    }
    bf16x8 af[2], bfr[4];
    #pragma unroll
    for (int m=0;m<2;m++) {
      int r = wr*32 + m*16 + lr;
      af[m] = *(const bf16x8*)(smA + r*64 + ((lh ^ ((r>>1)&3))<<4));
    }
    #pragma unroll
    for (int n=0;n<4;n++) {
      int r = wc*64 + n*16 + lr;
      bfr[n] = *(const bf16x8*)(smW + r*64 + ((lh ^ ((r>>1)&3))<<4));
    }
    #pragma unroll
    for (int m=0;m<2;m++)
      #pragma unroll
      for (int n=0;n<4;n++)
        acc[m][n] = __builtin_amdgcn_mfma_f32_16x16x32_bf16(af[m], bfr[n], acc[m][n], 0,0,0);
  }

  #pragma unroll
  for (int m=0;m<2;m++) {
    #pragma unroll
    for (int n=0;n<4;n++) {
      int col = bn + wc*64 + n*16 + lr;
      if (col >= N) continue;
      #pragma unroll
      for (int j=0;j<4;j++) {
        int row = bm + wr*32 + m*16 + lh*4 + j;
        float v = acc[m][n][j];
        size_t idx = (size_t)row*N + col;
        if      (EPI == EPI_BIAS_BF)     Cb[idx] = f2bf(v + bias[col]);
        else if (EPI == EPI_GELU_ADD_BF) Cb[idx] = f2bf(geluf_(v) + bf2f(Rb[idx]));
        else if (EPI == EPI_XZ)          Cb[idx] = f2bf(v);
        else                             Cf[idx] = v;
      }
    }
  }
}

// ---------------- fused fp32 -> bf16 casts (x + all weights) ----------------
__global__ __launch_bounds__(256) void cast_all_k(
    const float* __restrict__ x, const float* __restrict__ encw,
    const float* __restrict__ inw, const float* __restrict__ xw,
    const float* __restrict__ ow,
    ushort_t* __restrict__ xb, ushort_t* __restrict__ encwb,
    ushort_t* __restrict__ inwb, ushort_t* __restrict__ xwb,
    ushort_t* __restrict__ owb)
{
  int e0 = (blockIdx.x*256 + threadIdx.x) * 4;
  const float* src; ushort_t* dst; int off;
  if      (e0 < 1048576) { src=x;    dst=xb;    off=e0; }
  else if (e0 < 1081344) { src=encw; dst=encwb; off=e0-1048576; }
  else if (e0 < 1605632) { src=inw;  dst=inwb;  off=e0-1081344; }
  else if (e0 < 1654784) { src=xw;   dst=xwb;   off=e0-1605632; }
  else if (e0 < 1916928) { src=ow;   dst=owb;   off=e0-1654784; }
  else return;
  float4 v = *(const float4*)(src + off);
  ushort4 o; o.x=f2bf(v.x); o.y=f2bf(v.y); o.z=f2bf(v.z); o.w=f2bf(v.w);
  *(ushort4*)(dst + off) = o;
}

// prenorm layernorm on bf16 residual -> bf16 out
__global__ __launch_bounds__(256) void ln_k(const ushort_t* __restrict__ x,
    const float* __restrict__ w, const float* __restrict__ bb, ushort_t* __restrict__ y)
{
  int lane = threadIdx.x & 63;
  int wv = threadIdx.x >> 6;
  size_t row = (size_t)blockIdx.x*4 + wv;
  ushort4 v4 = ((const ushort4*)(x + row*DMODEL))[lane];
  float vx=bf2f(v4.x), vy=bf2f(v4.y), vz=bf2f(v4.z), vw=bf2f(v4.w);
  float s = vx+vy+vz+vw;
  #pragma unroll
  for (int off=32; off; off>>=1) s += __shfl_xor(s, off);
  float mean = s * (1.f/DMODEL);
  float d0=vx-mean, d1=vy-mean, d2=vz-mean, d3=vw-mean;
  float q = d0*d0+d1*d1+d2*d2+d3*d3;
  #pragma unroll
  for (int off=32; off; off>>=1) q += __shfl_xor(q, off);
  float rs = rsqrtf(q*(1.f/DMODEL) + 1e-5f);
  float4 w4 = ((const float4*)w)[lane];
  float4 b4 = ((const float4*)bb)[lane];
  ushort4 o;
  o.x = f2bf(d0*rs*w4.x + b4.x);
  o.y = f2bf(d1*rs*w4.y + b4.y);
  o.z = f2bf(d2*rs*w4.z + b4.z);
  o.w = f2bf(d3*rs*w4.w + b4.w);
  ((ushort4*)(y + row*DMODEL))[lane] = o;
}

// depthwise causal conv (k=4) + bias + silu -> bf16 xi. 4 d per thread.
__global__ __launch_bounds__(256) void conv_silu_k(
    const ushort_t* __restrict__ xz, const float* __restrict__ cw,
    const float* __restrict__ cb, ushort_t* __restrict__ xib)
{
  int idx = blockIdx.x*256 + threadIdx.x;   // over BL*DINNER/4
  int d0 = (idx & 127) * 4;
  int bl = idx >> 7;
  int l  = bl & (SEQL-1);
  const float4* cw4 = (const float4*)(cw + d0*4);   // 4 taps x 4 d
  float4 w0 = cw4[0], w1 = cw4[1], w2 = cw4[2], w3 = cw4[3];
  float4 cbv = *(const float4*)(cb + d0);
  const ushort_t* p = xz + (size_t)bl*(2*DINNER) + d0;
  ushort4 t0 = *(const ushort4*)(p);
  ushort4 t1 = (l>=1) ? *(const ushort4*)(p-1024) : make_ushort4(0,0,0,0);
  ushort4 t2 = (l>=2) ? *(const ushort4*)(p-2048) : make_ushort4(0,0,0,0);
  ushort4 t3 = (l>=3) ? *(const ushort4*)(p-3072) : make_ushort4(0,0,0,0);
  float a0 = cbv.x + bf2f(t0.x)*w0.w + bf2f(t1.x)*w0.z + bf2f(t2.x)*w0.y + bf2f(t3.x)*w0.x;
  float a1 = cbv.y + bf2f(t0.y)*w1.w + bf2f(t1.y)*w1.z + bf2f(t2.y)*w1.y + bf2f(t3.y)*w1.x;
  float a2 = cbv.z + bf2f(t0.z)*w2.w + bf2f(t1.z)*w2.z + bf2f(t2.z)*w2.y + bf2f(t3.z)*w2.x;
  float a3 = cbv.w + bf2f(t0.w)*w3.w + bf2f(t1.w)*w3.z + bf2f(t2.w)*w3.y + bf2f(t3.w)*w3.x;
  ushort4 o;
  o.x = f2bf(siluf_(a0)); o.y = f2bf(siluf_(a1));
  o.z = f2bf(siluf_(a2)); o.w = f2bf(siluf_(a3));
  *(ushort4*)(xib + (size_t)bl*DINNER + d0) = o;
}

// ---- chunked selective scan; dt-projection inline (dt adjacent to B/C in dbl) ----
__global__ __launch_bounds__(256) void scan1_k(
    const ushort_t* __restrict__ xib, const float* __restrict__ dbl,
    const float* __restrict__ dtw, const float* __restrict__ dtb,
    const float* __restrict__ A_log,
    float* __restrict__ S_out, ushort_t* __restrict__ Hloc)
{
  int blk = blockIdx.x;
  int half = blk & 1;
  int c = (blk >> 1) & (NCHUNK-1);
  int b = blk >> 8;
  int d = half*256 + threadIdx.x;
  float A[16], wv[16];
  #pragma unroll
  for (int n=0;n<16;n++) A[n] = -__expf(A_log[d*16+n]);
  #pragma unroll
  for (int k=0;k<16;k++) wv[k] = dtw[d*16+k];
  float bdt = dtb[d];
  bool fast = true;
  #pragma unroll
  for (int n=0;n<16;n++) fast = fast && (fabsf(A[n] + (float)(n+1)) <= 1e-3f*(n+1));
  float h[16] = {};
  float S = 0.f;
  size_t row0 = (size_t)b*SEQL + c*CHLEN;
  #pragma unroll 4
  for (int t=0;t<CHLEN;t++) {
    size_t row = row0 + t;
    const float4* q4 = (const float4*)(dbl + row*48);
    float4 d0 = q4[0], d1 = q4[1], d2 = q4[2], d3 = q4[3];
    float4 B0 = q4[4], B1 = q4[5], B2 = q4[6], B3 = q4[7];
    float u = bf2f(xib[row*DINNER + d]);
    float a0 = fmaf(d0.x,wv[0], bdt), a1 = fmaf(d0.y,wv[1], 0.f);
    float a2 = fmaf(d0.z,wv[2], 0.f), a3 = fmaf(d0.w,wv[3], 0.f);
    a0 = fmaf(d1.x,wv[4],a0); a1 = fmaf(d1.y,wv[5],a1);
    a2 = fmaf(d1.z,wv[6],a2); a3 = fmaf(d1.w,wv[7],a3);
    a0 = fmaf(d2.x,wv[8],a0); a1 = fmaf(d2.y,wv[9],a1);
    a2 = fmaf(d2.z,wv[10],a2); a3 = fmaf(d2.w,wv[11],a3);
    a0 = fmaf(d3.x,wv[12],a0); a1 = fmaf(d3.y,wv[13],a1);
    a2 = fmaf(d3.z,wv[14],a2); a3 = fmaf(d3.w,wv[15],a3);
    float dlt = softplusf_((a0+a1)+(a2+a3));
    S += dlt;
    float du = dlt*u;
    float Bv[16] = {B0.x,B0.y,B0.z,B0.w, B1.x,B1.y,B1.z,B1.w,
                    B2.x,B2.y,B2.z,B2.w, B3.x,B3.y,B3.z,B3.w};
    if (fast) {
      float p[16];
      pow16_(__expf(-dlt), p);
      #pragma unroll
      for (int n=0;n<16;n++) h[n] = fmaf(p[n], h[n], du*Bv[n]);
    } else {
      #pragma unroll
      for (int n=0;n<16;n++) {
        float dA = __expf(dlt*A[n]);
        h[n] = fmaf(dA, h[n], du*Bv[n]);
      }
    }
  }
  size_t base = (size_t)(b*NCHUNK + c)*DINNER + d;
  S_out[base] = S;
  #pragma unroll
  for (int q=0;q<4;q++) {
    ushort4 hv;
    hv.x = f2bf(h[4*q+0]); hv.y = f2bf(h[4*q+1]);
    hv.z = f2bf(h[4*q+2]); hv.w = f2bf(h[4*q+3]);
    *(ushort4*)(Hloc + base*16 + q*4) = hv;
  }
}

// sequential combine over chunks, software-pipelined groups of 4.
__global__ __launch_bounds__(128) void scomb_k(
    const float* __restrict__ S_arr, const ushort_t* __restrict__ Hl,
    ushort_t* __restrict__ Hinit, const float* __restrict__ A_log)
{
  int idx = blockIdx.x*128 + threadIdx.x;   // over BATCH*DINNER*16 = 32768
  int n = idx & 15;
  int d = (idx >> 4) & (DINNER-1);
  int b = idx >> 13;
  float A = -__expf(A_log[d*16+n]);
  size_t base0 = (size_t)b*NCHUNK*DINNER + d;
  float h = 0.f;
  for (int c=0;c<NCHUNK;c+=4) {
    float S[4], g[4];
    #pragma unroll
    for (int j=0;j<4;j++) {
      size_t bb = base0 + (size_t)(c+j)*DINNER;
      S[j] = S_arr[bb];
      g[j] = bf2f(Hl[bb*16 + n]);
    }
    float e0 = __expf(A*S[0]), e1 = __expf(A*S[1]);
    float e2 = __expf(A*S[2]), e3 = __expf(A*S[3]);
    #pragma unroll
    for (int j=0;j<4;j++) {
      size_t bb = base0 + (size_t)(c+j)*DINNER;
      Hinit[bb*16 + n] = f2bf(h);
      float e = (j==0)?e0:(j==1)?e1:(j==2)?e2:e3;
      h = fmaf(e, h, g[j]);
    }
  }
}

// phase2: replay with correct h0, dt-projection inline -> ys bf16
__global__ __launch_bounds__(256) void scan2_k(
    const ushort_t* __restrict__ xib, const float* __restrict__ dbl,
    const float* __restrict__ dtw, const float* __restrict__ dtb,
    const float* __restrict__ A_log,
    const ushort_t* __restrict__ Hinit, const float* __restrict__ Dp,
    const ushort_t* __restrict__ xz, ushort_t* __restrict__ ysb)
{
  int blk = blockIdx.x;
  int half = blk & 1;
  int c = (blk >> 1) & (NCHUNK-1);
  int b = blk >> 8;
  int d = half*256 + threadIdx.x;
  float A[16], wv[16];
  #pragma unroll
  for (int n=0;n<16;n++) A[n] = -__expf(A_log[d*16+n]);
  #pragma unroll
  for (int k=0;k<16;k++) wv[k] = dtw[d*16+k];
  float bdt = dtb[d];
  bool fast = true;
  #pragma unroll
  for (int n=0;n<16;n++) fast = fast && (fabsf(A[n] + (float)(n+1)) <= 1e-3f*(n+1));
  float Dd = Dp[d];
  size_t base = (size_t)(b*NCHUNK + c)*DINNER + d;
  float h[16];
  #pragma unroll
  for (int q=0;q<4;q++) {
    ushort4 v = *(const ushort4*)(Hinit + base*16 + q*4);
    h[4*q]=bf2f(v.x); h[4*q+1]=bf2f(v.y); h[4*q+2]=bf2f(v.z); h[4*q+3]=bf2f(v.w);
  }
  size_t row0 = (size_t)b*SEQL + c*CHLEN;
  #pragma unroll 4
  for (int t=0;t<CHLEN;t++) {
    size_t row = row0 + t;
    const float4* q4 = (const float4*)(dbl + row*48);
    float4 d0 = q4[0], d1 = q4[1], d2 = q4[2], d3 = q4[3];
    float4 B0 = q4[4], B1 = q4[5], B2 = q4[6], B3 = q4[7];
    float4 C0 = q4[8], C1 = q4[9], C2 = q4[10], C3 = q4[11];
    float u = bf2f(xib[row*DINNER + d]);
    float a0 = fmaf(d0.x,wv[0], bdt), a1 = fmaf(d0.y,wv[1], 0.f);
    float a2 = fmaf(d0.z,wv[2], 0.f), a3 = fmaf(d0.w,wv[3], 0.f);
    a0 = fmaf(d1.x,wv[4],a0); a1 = fmaf(d1.y,wv[5],a1);
    a2 = fmaf(d1.z,wv[6],a2); a3 = fmaf(d1.w,wv[7],a3);
    a0 = fmaf(d2.x,wv[8],a0); a1 = fmaf(d2.y,wv[9],a1);
    a2 = fmaf(d2.z,wv[10],a2); a3 = fmaf(d2.w,wv[11],a3);
    a0 = fmaf(d3.x,wv[12],a0); a1 = fmaf(d3.y,wv[13],a1);
    a2 = fmaf(d3.z,wv[14],a2); a3 = fmaf(d3.w,wv[15],a3);
    float dlt = softplusf_((a0+a1)+(a2+a3));
    float du = dlt*u;
    float Bv[16] = {B0.x,B0.y,B0.z,B0.w, B1.x,B1.y,B1.z,B1.w,
                    B2.x,B2.y,B2.z,B2.w, B3.x,B3.y,B3.z,B3.w};
    float Cv[16] = {C0.x,C0.y,C0.z,C0.w, C1.x,C1.y,C1.z,C1.w,
                    C2.x,C2.y,C2.z,C2.w, C3.x,C3.y,C3.z,C3.w};
    float y0=0.f, y1=0.f, y2=0.f, y3=0.f;
    if (fast) {
      float p[16];
      pow16_(__expf(-dlt), p);
      #pragma unroll
      for (int q=0;q<4;q++) {
        h[4*q+0] = fmaf(p[4*q+0], h[4*q+0], du*Bv[4*q+0]);
        h[4*q+1] = fmaf(p[4*q+1], h[4*q+1], du*Bv[4*q+1]);
        h[4*q+2] = fmaf(p[4*q+2], h[4*q+2], du*Bv[4*q+2]);
        h[4*q+3] = fmaf(p[4*q+3], h[4*q+3], du*Bv[4*q+3]);
        y0 = fmaf(h[4*q+0], Cv[4*q+0], y0);
        y1 = fmaf(h[4*q+1], Cv[4*q+1], y1);
        y2 = fmaf(h[4*q+2], Cv[4*q+2], y2);
        y3 = fmaf(h[4*q+3], Cv[4*q+3], y3);
      }
    } else {
      #pragma unroll
      for (int q=0;q<4;q++) {
        float dA0 = __expf(dlt*A[4*q+0]);
        float dA1 = __expf(dlt*A[4*q+1]);
        float dA2 = __expf(dlt*A[4*q+2]);
        float dA3 = __expf(dlt*A[4*q+3]);
        h[4*q+0] = fmaf(dA0, h[4*q+0], du*Bv[4*q+0]);
        h[4*q+1] = fmaf(dA1, h[4*q+1], du*Bv[4*q+1]);
        h[4*q+2] = fmaf(dA2, h[4*q+2], du*Bv[4*q+2]);
        h[4*q+3] = fmaf(dA3, h[4*q+3], du*Bv[4*q+3]);
        y0 = fmaf(h[4*q+0], Cv[4*q+0], y0);
        y1 = fmaf(h[4*q+1], Cv[4*q+1], y1);
        y2 = fmaf(h[4*q+2], Cv[4*q+2], y2);
        y3 = fmaf(h[4*q+3], Cv[4*q+3], y3);
      }
    }
    float y = fmaf(u, Dd, (y0+y1)+(y2+y3));
    float z = bf2f(xz[row*1024 + 512 + d]);
    ysb[row*DINNER + d] = f2bf(y * siluf_(z));
  }
}

// partial pool over bf16 residual
__global__ void pool1_k(const ushort_t* __restrict__ h, float* __restrict__ part)
{
  int b = blockIdx.x, seg = blockIdx.y, d = threadIdx.x;
  float s = 0.f;
  size_t base = ((size_t)b*SEQL + seg*64)*DMODEL + d;
  for (int l=0;l<64;l++) s += bf2f(h[base + (size_t)l*DMODEL]);
  part[(b*32+seg)*DMODEL + d] = s;
}

// fused pool2 + decoder + softmax (one block, 1024 threads)
__global__ __launch_bounds__(1024) void pooldec_k(
    const float* __restrict__ part, const float* __restrict__ dw,
    const float* __restrict__ db, float* __restrict__ out)
{
  __shared__ float pooled[1024];
  __shared__ float lg[40];
  int t = threadIdx.x;
  int b = t >> 8, d = t & 255;
  float s = 0.f;
  for (int g=0; g<32; g++) s += part[(b*32+g)*DMODEL + d];
  pooled[b*DMODEL + d] = s * (1.f/SEQL);
  __syncthreads();
  if (t < 40) {
    int bb = t/10, o = t%10;
    float acc = db[o];
    const float* pv = pooled + bb*DMODEL;
    const float* wv = dw + o*DMODEL;
    for (int k=0;k<DMODEL;k++) acc = fmaf(pv[k], wv[k], acc);
    lg[t] = acc;
  }
  __syncthreads();
  if (t < 4) {
    float mx = -1e30f;
    for (int o=0;o<10;o++) mx = fmaxf(mx, lg[t*10+o]);
    float e[10]; float ss = 0.f;
    for (int o=0;o<10;o++) { e[o] = __expf(lg[t*10+o]-mx); ss += e[o]; }
    float inv = 1.f/ss;
    for (int o=0;o<10;o++) out[t*10+o] = e[o]*inv;
  }
}

extern "C" void kernel_launch(void* const* d_in, const int* in_sizes, int n_in,
                              void* d_out, int out_size, void* d_ws, size_t ws_size,
                              hipStream_t stream)
{
  const float* x      = (const float*)d_in[0];
  const float* enc_w  = (const float*)d_in[1];
  const float* enc_b  = (const float*)d_in[2];
  const float* ln_w   = (const float*)d_in[3];
  const float* ln_b   = (const float*)d_in[4];
  const float* inw    = (const float*)d_in[5];
  const float* cw     = (const float*)d_in[6];
  const float* cb     = (const float*)d_in[7];
  const float* xw     = (const float*)d_in[8];
  const float* dtw    = (const float*)d_in[9];
  const float* dtb    = (const float*)d_in[10];
  const float* A_log  = (const float*)d_in[11];
  const float* Dp     = (const float*)d_in[12];
  const float* ow     = (const float*)d_in[13];
  const float* dec_w  = (const float*)d_in[14];
  const float* dec_b  = (const float*)d_in[15];
  float* out = (float*)d_out;

  float* f = (float*)d_ws;
  float* b_dbl  = f; f += 393216;
  float* b_S    = f; f += 262144;
  float* b_part = f; f += 8192;
  ushort_t* u = (ushort_t*)f;
  ushort_t* hb    = u; u += 2097152;
  ushort_t* b_Hl  = u; u += 4194304;
  ushort_t* b_Hi  = u; u += 4194304;
  ushort_t* xb    = u; u += 1048576;
  ushort_t* encwb = u; u += 32768;
  ushort_t* inwb  = u; u += 524288;
  ushort_t* xwb   = u; u += 49152;
  ushort_t* owb   = u; u += 262144;
  ushort_t* lnb   = u; u += 2097152;
  ushort_t* xib   = u; u += 4194304;
  ushort_t* xzb   = u; u += 8388608;
  ushort_t* ysb   = u; u += 4194304;

  cast_all_k<<<1872, 256, 0, stream>>>(x, enc_w, inw, xw, ow,
                                       xb, encwb, inwb, xwb, owb);

  bgemm64<EPI_BIAS_BF><<<dim3(BLROWS/64, 2), 256, 0, stream>>>(
      xb, encwb, enc_b, nullptr, hb, BLROWS, DMODEL, 128);

  for (int i=0;i<2;i++) {
    const float* cwi = cw + i*DINNER*4;
    const float* cbi = cb + i*DINNER;
    const float* dtwi = dtw + (size_t)i*DINNER*16;
    const float* dtbi = dtb + i*DINNER;
    const float* Ai = A_log + (size_t)i*DINNER*16;
    ln_k<<<BLROWS/4, 256, 0, stream>>>(hb, ln_w + i*DMODEL, ln_b + i*DMODEL, lnb);
    bgemm128<EPI_XZ><<<dim3(BLROWS/128, 8), 256, 0, stream>>>(
        lnb, inwb + (size_t)i*262144, nullptr, nullptr, xzb, BLROWS, 1024, DMODEL);
    conv_silu_k<<<(BLROWS*DINNER/4)/256, 256, 0, stream>>>(xzb, cwi, cbi, xib);
    bgemm64<EPI_NONE><<<dim3(BLROWS/64, 1), 256, 0, stream>>>(
        xib, xwb + (size_t)i*24576, nullptr, nullptr, b_dbl, BLROWS, 48, DINNER);
    scan1_k<<<BATCH*NCHUNK*2, 256, 0, stream>>>(
        xib, b_dbl, dtwi, dtbi, Ai, b_S, b_Hl);
    scomb_k<<<256, 128, 0, stream>>>(b_S, b_Hl, b_Hi, Ai);
    scan2_k<<<BATCH*NCHUNK*2, 256, 0, stream>>>(
        xib, b_dbl, dtwi, dtbi, Ai, b_Hi, Dp + i*DINNER, xzb, ysb);
    bgemm64<EPI_GELU_ADD_BF><<<dim3(BLROWS/64, 2), 256, 0, stream>>>(
        ysb, owb + (size_t)i*131072, nullptr, hb, hb, BLROWS, DMODEL, DINNER);
  }
  pool1_k<<<dim3(BATCH,32), 256, 0, stream>>>(hb, b_part);
  pooldec_k<<<1, 1024, 0, stream>>>(b_part, dec_w, dec_b, out);
}

// Round 15
// 206.458 us; speedup vs baseline: 1.0448x; 1.0448x over previous
//
#include <hip/hip_runtime.h>
#include <math.h>

#define BATCH  4
#define SEQL   2048
#define BLROWS (BATCH*SEQL)     // 8192
#define DMODEL 256
#define DINNER 512
#define DSTATE 16
#define DTRANK 16
#define NCHUNK 128
#define CHLEN  (SEQL/NCHUNK)    // 16

typedef __attribute__((ext_vector_type(8))) __bf16 bf16x8;
typedef __attribute__((ext_vector_type(4))) float f32x4;
typedef unsigned short ushort_t;

__device__ __forceinline__ float sigmoidf_(float x) { return 1.f/(1.f+__expf(-x)); }
__device__ __forceinline__ float siluf_(float x)    { return x*sigmoidf_(x); }
__device__ __forceinline__ float softplusf_(float x){
  float e = __expf(-fabsf(x));
  return fmaxf(x, 0.f) + __logf(1.f + e);
}
__device__ __forceinline__ float geluf_(float x){
  const float c = 0.7978845608028654f;
  float t = c*(x + 0.044715f*x*x*x);
  float e = __expf(2.f*t);
  float th = 1.f - 2.f/(e + 1.f);
  return 0.5f*x*(1.f+th);
}
__device__ __forceinline__ ushort_t f2bf(float f){
  unsigned int u = __float_as_uint(f);
  u = (u + 0x7FFFu + ((u>>16)&1u)) >> 16;
  return (ushort_t)u;
}
__device__ __forceinline__ float bf2f(ushort_t b){
  return __uint_as_float(((unsigned int)b) << 16);
}
// p[n] = r^(n+1), tree depth ~4
__device__ __forceinline__ void pow16_(float r, float* p){
  float r2 = r*r, r4 = r2*r2, r8 = r4*r4;
  p[0]=r;      p[1]=r2;     p[2]=r2*r;   p[3]=r4;
  p[4]=r4*r;   p[5]=r4*r2;  p[6]=r4*p[2];p[7]=r8;
  p[8]=r8*r;   p[9]=r8*r2;  p[10]=r8*p[2];p[11]=r8*r4;
  p[12]=r8*p[4];p[13]=r8*p[5];p[14]=r8*p[6];p[15]=r8*r8;
}
__device__ __forceinline__ void unpack_(unsigned int p, float& dlt, float& u){
  dlt = __uint_as_float(p << 16);
  u   = __uint_as_float(p & 0xFFFF0000u);
}

enum { EPI_NONE=0, EPI_BIAS_BF=1, EPI_GELU_ADD_BF=3, EPI_XZ=4 };

// ---------------- bf16 MFMA GEMM, BM=128 BN=128 BK=32 ----------------
template<int EPI>
__global__ __launch_bounds__(256) void bgemm128(
    const ushort_t* __restrict__ A, const ushort_t* __restrict__ W,
    const float* __restrict__ bias, const void* __restrict__ Rv,
    void* __restrict__ Cv, int M, int N, int K)
{
  __shared__ __align__(16) char smA[8192];
  __shared__ __align__(16) char smW[8192];
  float* Cf = (float*)Cv;
  ushort_t* Cb = (ushort_t*)Cv;
  const ushort_t* Rb = (const ushort_t*)Rv;
  const int tid  = threadIdx.x;
  const int w    = tid >> 6;
  const int lane = tid & 63;
  const int lr = lane & 15, lh = lane >> 4;
  const int wr = w >> 1, wc = w & 1;
  const int bm = blockIdx.x * 128, bn = blockIdx.y * 128;

  const int srow  = tid >> 2;
  const int sslot = tid & 3;
  const int lslot = sslot ^ ((srow >> 1) & 3);
  const size_t aoff0 = (size_t)(bm + srow)      * K + lslot*8;
  const size_t aoff1 = (size_t)(bm + srow + 64) * K + lslot*8;
  const int wrow0 = bn + srow, wrow1 = bn + srow + 64;
  const size_t woff0 = (size_t)wrow0 * K + lslot*8;
  const size_t woff1 = (size_t)wrow1 * K + lslot*8;

  f32x4 acc[4][4];
  #pragma unroll
  for (int m=0;m<4;m++)
    #pragma unroll
    for (int n=0;n<4;n++) acc[m][n] = (f32x4){0.f,0.f,0.f,0.f};

  int4 ar0, ar1, br0, br1;
  const int4 z4 = make_int4(0,0,0,0);
  ar0 = *(const int4*)(A + aoff0);
  ar1 = *(const int4*)(A + aoff1);
  br0 = (wrow0 < N) ? *(const int4*)(W + woff0) : z4;
  br1 = (wrow1 < N) ? *(const int4*)(W + woff1) : z4;

  for (int k0 = 0; k0 < K; k0 += 32) {
    __syncthreads();
    *(int4*)(smA +        tid*16) = ar0;
    *(int4*)(smA + 4096 + tid*16) = ar1;
    *(int4*)(smW +        tid*16) = br0;
    *(int4*)(smW + 4096 + tid*16) = br1;
    __syncthreads();
    if (k0 + 32 < K) {
      int k1 = k0 + 32;
      ar0 = *(const int4*)(A + aoff0 + k1);
      ar1 = *(const int4*)(A + aoff1 + k1);
      br0 = (wrow0 < N) ? *(const int4*)(W + woff0 + k1) : z4;
      br1 = (wrow1 < N) ? *(const int4*)(W + woff1 + k1) : z4;
    }
    bf16x8 af[4], bfr[4];
    #pragma unroll
    for (int m=0;m<4;m++) {
      int r = wr*64 + m*16 + lr;
      af[m] = *(const bf16x8*)(smA + r*64 + ((lh ^ ((r>>1)&3))<<4));
    }
    #pragma unroll
    for (int n=0;n<4;n++) {
      int r = wc*64 + n*16 + lr;
      bfr[n] = *(const bf16x8*)(smW + r*64 + ((lh ^ ((r>>1)&3))<<4));
    }
    #pragma unroll
    for (int m=0;m<4;m++)
      #pragma unroll
      for (int n=0;n<4;n++)
        acc[m][n] = __builtin_amdgcn_mfma_f32_16x16x32_bf16(af[m], bfr[n], acc[m][n], 0,0,0);
  }

  #pragma unroll
  for (int m=0;m<4;m++) {
    #pragma unroll
    for (int n=0;n<4;n++) {
      int col = bn + wc*64 + n*16 + lr;
      if (col >= N) continue;
      #pragma unroll
      for (int j=0;j<4;j++) {
        int row = bm + wr*64 + m*16 + lh*4 + j;
        float v = acc[m][n][j];
        size_t idx = (size_t)row*N + col;
        if      (EPI == EPI_BIAS_BF)     Cb[idx] = f2bf(v + bias[col]);
        else if (EPI == EPI_GELU_ADD_BF) Cb[idx] = f2bf(geluf_(v) + bf2f(Rb[idx]));
        else if (EPI == EPI_XZ)          Cb[idx] = f2bf(v);
        else                             Cf[idx] = v;
      }
    }
  }
}

// ---------------- bf16 MFMA GEMM, BM=64 BN=128 BK=32 ----------------
template<int EPI>
__global__ __launch_bounds__(256) void bgemm64(
    const ushort_t* __restrict__ A, const ushort_t* __restrict__ W,
    const float* __restrict__ bias, const void* __restrict__ Rv,
    void* __restrict__ Cv, int M, int N, int K)
{
  __shared__ __align__(16) char smA[4096];
  __shared__ __align__(16) char smW[8192];
  float* Cf = (float*)Cv;
  ushort_t* Cb = (ushort_t*)Cv;
  const ushort_t* Rb = (const ushort_t*)Rv;
  const int tid  = threadIdx.x;
  const int w    = tid >> 6;
  const int lane = tid & 63;
  const int lr = lane & 15, lh = lane >> 4;
  const int wr = w >> 1, wc = w & 1;
  const int bm = blockIdx.x * 64, bn = blockIdx.y * 128;

  const int srow  = tid >> 2;
  const int sslot = tid & 3;
  const int lslot = sslot ^ ((srow >> 1) & 3);
  const size_t aoff  = (size_t)(bm + srow) * K + lslot*8;
  const int wrow0 = bn + srow, wrow1 = bn + srow + 64;
  const size_t woff0 = (size_t)wrow0 * K + lslot*8;
  const size_t woff1 = (size_t)wrow1 * K + lslot*8;

  f32x4 acc[2][4];
  #pragma unroll
  for (int m=0;m<2;m++)
    #pragma unroll
    for (int n=0;n<4;n++) acc[m][n] = (f32x4){0.f,0.f,0.f,0.f};

  int4 ar, br0, br1;
  const int4 z4 = make_int4(0,0,0,0);
  ar  = *(const int4*)(A + aoff);
  br0 = (wrow0 < N) ? *(const int4*)(W + woff0) : z4;
  br1 = (wrow1 < N) ? *(const int4*)(W + woff1) : z4;

  for (int k0 = 0; k0 < K; k0 += 32) {
    __syncthreads();
    *(int4*)(smA + tid*16)        = ar;
    *(int4*)(smW + tid*16)        = br0;
    *(int4*)(smW + 4096 + tid*16) = br1;
    __syncthreads();
    if (k0 + 32 < K) {
      int k1 = k0 + 32;
      ar  = *(const int4*)(A + aoff + k1);
      br0 = (wrow0 < N) ? *(const int4*)(W + woff0 + k1) : z4;
      br1 = (wrow1 < N) ? *(const int4*)(W + woff1 + k1) : z4;
    }
    bf16x8 af[2], bfr[4];
    #pragma unroll
    for (int m=0;m<2;m++) {
      int r = wr*32 + m*16 + lr;
      af[m] = *(const bf16x8*)(smA + r*64 + ((lh ^ ((r>>1)&3))<<4));
    }
    #pragma unroll
    for (int n=0;n<4;n++) {
      int r = wc*64 + n*16 + lr;
      bfr[n] = *(const bf16x8*)(smW + r*64 + ((lh ^ ((r>>1)&3))<<4));
    }
    #pragma unroll
    for (int m=0;m<2;m++)
      #pragma unroll
      for (int n=0;n<4;n++)
        acc[m][n] = __builtin_amdgcn_mfma_f32_16x16x32_bf16(af[m], bfr[n], acc[m][n], 0,0,0);
  }

  #pragma unroll
  for (int m=0;m<2;m++) {
    #pragma unroll
    for (int n=0;n<4;n++) {
      int col = bn + wc*64 + n*16 + lr;
      if (col >= N) continue;
      #pragma unroll
      for (int j=0;j<4;j++) {
        int row = bm + wr*32 + m*16 + lh*4 + j;
        float v = acc[m][n][j];
        size_t idx = (size_t)row*N + col;
        if      (EPI == EPI_BIAS_BF)     Cb[idx] = f2bf(v + bias[col]);
        else if (EPI == EPI_GELU_ADD_BF) Cb[idx] = f2bf(geluf_(v) + bf2f(Rb[idx]));
        else if (EPI == EPI_XZ)          Cb[idx] = f2bf(v);
        else                             Cf[idx] = v;
      }
    }
  }
}

// ---------------- fused fp32 -> bf16 casts (x + all weights) ----------------
__global__ __launch_bounds__(256) void cast_all_k(
    const float* __restrict__ x, const float* __restrict__ encw,
    const float* __restrict__ inw, const float* __restrict__ xw,
    const float* __restrict__ ow,
    ushort_t* __restrict__ xb, ushort_t* __restrict__ encwb,
    ushort_t* __restrict__ inwb, ushort_t* __restrict__ xwb,
    ushort_t* __restrict__ owb)
{
  int e0 = (blockIdx.x*256 + threadIdx.x) * 4;
  const float* src; ushort_t* dst; int off;
  if      (e0 < 1048576) { src=x;    dst=xb;    off=e0; }
  else if (e0 < 1081344) { src=encw; dst=encwb; off=e0-1048576; }
  else if (e0 < 1605632) { src=inw;  dst=inwb;  off=e0-1081344; }
  else if (e0 < 1654784) { src=xw;   dst=xwb;   off=e0-1605632; }
  else if (e0 < 1916928) { src=ow;   dst=owb;   off=e0-1654784; }
  else return;
  float4 v = *(const float4*)(src + off);
  ushort4 o; o.x=f2bf(v.x); o.y=f2bf(v.y); o.z=f2bf(v.z); o.w=f2bf(v.w);
  *(ushort4*)(dst + off) = o;
}

// prenorm layernorm on bf16 residual -> bf16 out
__global__ __launch_bounds__(256) void ln_k(const ushort_t* __restrict__ x,
    const float* __restrict__ w, const float* __restrict__ bb, ushort_t* __restrict__ y)
{
  int lane = threadIdx.x & 63;
  int wv = threadIdx.x >> 6;
  size_t row = (size_t)blockIdx.x*4 + wv;
  ushort4 v4 = ((const ushort4*)(x + row*DMODEL))[lane];
  float vx=bf2f(v4.x), vy=bf2f(v4.y), vz=bf2f(v4.z), vw=bf2f(v4.w);
  float s = vx+vy+vz+vw;
  #pragma unroll
  for (int off=32; off; off>>=1) s += __shfl_xor(s, off);
  float mean = s * (1.f/DMODEL);
  float d0=vx-mean, d1=vy-mean, d2=vz-mean, d3=vw-mean;
  float q = d0*d0+d1*d1+d2*d2+d3*d3;
  #pragma unroll
  for (int off=32; off; off>>=1) q += __shfl_xor(q, off);
  float rs = rsqrtf(q*(1.f/DMODEL) + 1e-5f);
  float4 w4 = ((const float4*)w)[lane];
  float4 b4 = ((const float4*)bb)[lane];
  ushort4 o;
  o.x = f2bf(d0*rs*w4.x + b4.x);
  o.y = f2bf(d1*rs*w4.y + b4.y);
  o.z = f2bf(d2*rs*w4.z + b4.z);
  o.w = f2bf(d3*rs*w4.w + b4.w);
  ((ushort4*)(y + row*DMODEL))[lane] = o;
}

// depthwise causal conv (k=4) + bias + silu -> bf16 xi. 4 d per thread.
__global__ __launch_bounds__(256) void conv_silu_k(
    const ushort_t* __restrict__ xz, const float* __restrict__ cw,
    const float* __restrict__ cb, ushort_t* __restrict__ xib)
{
  int idx = blockIdx.x*256 + threadIdx.x;   // over BL*DINNER/4
  int d0 = (idx & 127) * 4;
  int bl = idx >> 7;
  int l  = bl & (SEQL-1);
  const float4* cw4 = (const float4*)(cw + d0*4);   // 4 taps x 4 d
  float4 w0 = cw4[0], w1 = cw4[1], w2 = cw4[2], w3 = cw4[3];
  float4 cbv = *(const float4*)(cb + d0);
  const ushort_t* p = xz + (size_t)bl*(2*DINNER) + d0;
  ushort4 t0 = *(const ushort4*)(p);
  ushort4 t1 = (l>=1) ? *(const ushort4*)(p-1024) : make_ushort4(0,0,0,0);
  ushort4 t2 = (l>=2) ? *(const ushort4*)(p-2048) : make_ushort4(0,0,0,0);
  ushort4 t3 = (l>=3) ? *(const ushort4*)(p-3072) : make_ushort4(0,0,0,0);
  float a0 = cbv.x + bf2f(t0.x)*w0.w + bf2f(t1.x)*w0.z + bf2f(t2.x)*w0.y + bf2f(t3.x)*w0.x;
  float a1 = cbv.y + bf2f(t0.y)*w1.w + bf2f(t1.y)*w1.z + bf2f(t2.y)*w1.y + bf2f(t3.y)*w1.x;
  float a2 = cbv.z + bf2f(t0.z)*w2.w + bf2f(t1.z)*w2.z + bf2f(t2.z)*w2.y + bf2f(t3.z)*w2.x;
  float a3 = cbv.w + bf2f(t0.w)*w3.w + bf2f(t1.w)*w3.z + bf2f(t2.w)*w3.y + bf2f(t3.w)*w3.x;
  ushort4 o;
  o.x = f2bf(siluf_(a0)); o.y = f2bf(siluf_(a1));
  o.z = f2bf(siluf_(a2)); o.w = f2bf(siluf_(a3));
  *(ushort4*)(xib + (size_t)bl*DINNER + d0) = o;
}

// delta+pack: pair[row,d] = (bf16 delta) | (bf16 u)<<16
__global__ __launch_bounds__(256) void delta_k(
    const float* __restrict__ dbl, const float* __restrict__ dtw,
    const float* __restrict__ dtb, const ushort_t* __restrict__ xib,
    unsigned int* __restrict__ pair)
{
  int tid = threadIdx.x;
  float w0[16], w1[16];
  #pragma unroll
  for (int k=0;k<16;k++) { w0[k] = dtw[tid*16+k]; w1[k] = dtw[(tid+256)*16+k]; }
  float b0 = dtb[tid], b1 = dtb[tid+256];
  int m0 = blockIdx.x * 8;
  for (int r=0;r<8;r++) {
    const float4* dt4 = (const float4*)(dbl + (size_t)(m0+r)*48);
    float4 v0 = dt4[0], v1 = dt4[1], v2 = dt4[2], v3 = dt4[3];
    float dt[16] = {v0.x,v0.y,v0.z,v0.w, v1.x,v1.y,v1.z,v1.w,
                    v2.x,v2.y,v2.z,v2.w, v3.x,v3.y,v3.z,v3.w};
    float a0=b0, a1=0.f, a2=0.f, a3=0.f;
    float c0=b1, c1=0.f, c2=0.f, c3=0.f;
    #pragma unroll
    for (int k=0;k<4;k++) {
      float t0=dt[4*k+0], t1=dt[4*k+1], t2=dt[4*k+2], t3=dt[4*k+3];
      a0 = fmaf(t0, w0[4*k+0], a0); a1 = fmaf(t1, w0[4*k+1], a1);
      a2 = fmaf(t2, w0[4*k+2], a2); a3 = fmaf(t3, w0[4*k+3], a3);
      c0 = fmaf(t0, w1[4*k+0], c0); c1 = fmaf(t1, w1[4*k+1], c1);
      c2 = fmaf(t2, w1[4*k+2], c2); c3 = fmaf(t3, w1[4*k+3], c3);
    }
    size_t o = (size_t)(m0+r)*DINNER;
    unsigned int d0 = (unsigned int)f2bf(softplusf_((a0+a1)+(a2+a3)));
    unsigned int d1 = (unsigned int)f2bf(softplusf_((c0+c1)+(c2+c3)));
    pair[o + tid]       = d0 | ((unsigned int)xib[o + tid]       << 16);
    pair[o + tid + 256] = d1 | ((unsigned int)xib[o + tid + 256] << 16);
  }
}

// ---- chunked selective scan; reads packed (delta,u), float4 B/C loads ----
__global__ __launch_bounds__(256) void scan1_k(
    const unsigned int* __restrict__ pair,
    const float* __restrict__ dbl, const float* __restrict__ A_log,
    float* __restrict__ S_out, ushort_t* __restrict__ Hloc)
{
  int blk = blockIdx.x;
  int half = blk & 1;
  int c = (blk >> 1) & (NCHUNK-1);
  int b = blk >> 8;
  int d = half*256 + threadIdx.x;
  float A[16];
  #pragma unroll
  for (int n=0;n<16;n++) A[n] = -__expf(A_log[d*16+n]);
  bool fast = true;
  #pragma unroll
  for (int n=0;n<16;n++) fast = fast && (fabsf(A[n] + (float)(n+1)) <= 1e-3f*(n+1));
  float h[16] = {};
  float S = 0.f;
  size_t row0 = (size_t)b*SEQL + c*CHLEN;
  if (fast) {
    #pragma unroll 4
    for (int t=0;t<CHLEN;t++) {
      size_t row = row0 + t;
      float dlt, u;
      unpack_(pair[row*DINNER + d], dlt, u);
      S += dlt;
      float du = dlt*u;
      const float4* B4 = (const float4*)(dbl + row*48 + DTRANK);
      float4 v0 = B4[0], v1 = B4[1], v2 = B4[2], v3 = B4[3];
      float Bv[16] = {v0.x,v0.y,v0.z,v0.w, v1.x,v1.y,v1.z,v1.w,
                      v2.x,v2.y,v2.z,v2.w, v3.x,v3.y,v3.z,v3.w};
      float p[16];
      pow16_(__expf(-dlt), p);
      #pragma unroll
      for (int n=0;n<16;n++) h[n] = fmaf(p[n], h[n], du*Bv[n]);
    }
  } else {
    #pragma unroll 4
    for (int t=0;t<CHLEN;t++) {
      size_t row = row0 + t;
      float dlt, u;
      unpack_(pair[row*DINNER + d], dlt, u);
      S += dlt;
      float du = dlt*u;
      const float4* B4 = (const float4*)(dbl + row*48 + DTRANK);
      float4 v0 = B4[0], v1 = B4[1], v2 = B4[2], v3 = B4[3];
      float Bv[16] = {v0.x,v0.y,v0.z,v0.w, v1.x,v1.y,v1.z,v1.w,
                      v2.x,v2.y,v2.z,v2.w, v3.x,v3.y,v3.z,v3.w};
      #pragma unroll
      for (int n=0;n<16;n++) {
        float dA = __expf(dlt*A[n]);
        h[n] = fmaf(dA, h[n], du*Bv[n]);
      }
    }
  }
  size_t base = (size_t)(b*NCHUNK + c)*DINNER + d;
  S_out[base] = S;
  #pragma unroll
  for (int q=0;q<4;q++) {
    ushort4 hv;
    hv.x = f2bf(h[4*q+0]); hv.y = f2bf(h[4*q+1]);
    hv.z = f2bf(h[4*q+2]); hv.w = f2bf(h[4*q+3]);
    *(ushort4*)(Hloc + base*16 + q*4) = hv;
  }
}

// sequential combine over chunks, software-pipelined groups of 4.
__global__ __launch_bounds__(128) void scomb_k(
    const float* __restrict__ S_arr, const ushort_t* __restrict__ Hl,
    ushort_t* __restrict__ Hinit, const float* __restrict__ A_log)
{
  int idx = blockIdx.x*128 + threadIdx.x;   // over BATCH*DINNER*16 = 32768
  int n = idx & 15;
  int d = (idx >> 4) & (DINNER-1);
  int b = idx >> 13;
  float A = -__expf(A_log[d*16+n]);
  size_t base0 = (size_t)b*NCHUNK*DINNER + d;
  float h = 0.f;
  for (int c=0;c<NCHUNK;c+=4) {
    float S[4], g[4];
    #pragma unroll
    for (int j=0;j<4;j++) {
      size_t bb = base0 + (size_t)(c+j)*DINNER;
      S[j] = S_arr[bb];
      g[j] = bf2f(Hl[bb*16 + n]);
    }
    float e0 = __expf(A*S[0]), e1 = __expf(A*S[1]);
    float e2 = __expf(A*S[2]), e3 = __expf(A*S[3]);
    #pragma unroll
    for (int j=0;j<4;j++) {
      size_t bb = base0 + (size_t)(c+j)*DINNER;
      Hinit[bb*16 + n] = f2bf(h);
      float e = (j==0)?e0:(j==1)?e1:(j==2)?e2:e3;
      h = fmaf(e, h, g[j]);
    }
  }
}

// phase2: replay with correct h0 -> ys bf16
__global__ __launch_bounds__(256) void scan2_k(
    const unsigned int* __restrict__ pair,
    const float* __restrict__ dbl, const float* __restrict__ A_log,
    const ushort_t* __restrict__ Hinit, const float* __restrict__ Dp,
    const ushort_t* __restrict__ xz, ushort_t* __restrict__ ysb)
{
  int blk = blockIdx.x;
  int half = blk & 1;
  int c = (blk >> 1) & (NCHUNK-1);
  int b = blk >> 8;
  int d = half*256 + threadIdx.x;
  float A[16];
  #pragma unroll
  for (int n=0;n<16;n++) A[n] = -__expf(A_log[d*16+n]);
  bool fast = true;
  #pragma unroll
  for (int n=0;n<16;n++) fast = fast && (fabsf(A[n] + (float)(n+1)) <= 1e-3f*(n+1));
  float Dd = Dp[d];
  size_t base = (size_t)(b*NCHUNK + c)*DINNER + d;
  float h[16];
  #pragma unroll
  for (int q=0;q<4;q++) {
    ushort4 v = *(const ushort4*)(Hinit + base*16 + q*4);
    h[4*q]=bf2f(v.x); h[4*q+1]=bf2f(v.y); h[4*q+2]=bf2f(v.z); h[4*q+3]=bf2f(v.w);
  }
  size_t row0 = (size_t)b*SEQL + c*CHLEN;
  if (fast) {
    #pragma unroll 4
    for (int t=0;t<CHLEN;t++) {
      size_t row = row0 + t;
      float dlt, u;
      unpack_(pair[row*DINNER + d], dlt, u);
      float du = dlt*u;
      const float4* q4 = (const float4*)(dbl + row*48 + DTRANK);
      float4 v0 = q4[0], v1 = q4[1], v2 = q4[2], v3 = q4[3];
      float4 c0 = q4[4], c1 = q4[5], c2 = q4[6], c3 = q4[7];
      float Bv[16] = {v0.x,v0.y,v0.z,v0.w, v1.x,v1.y,v1.z,v1.w,
                      v2.x,v2.y,v2.z,v2.w, v3.x,v3.y,v3.z,v3.w};
      float Cv[16] = {c0.x,c0.y,c0.z,c0.w, c1.x,c1.y,c1.z,c1.w,
                      c2.x,c2.y,c2.z,c2.w, c3.x,c3.y,c3.z,c3.w};
      float p[16];
      pow16_(__expf(-dlt), p);
      float y0=0.f, y1=0.f, y2=0.f, y3=0.f;
      #pragma unroll
      for (int q=0;q<4;q++) {
        h[4*q+0] = fmaf(p[4*q+0], h[4*q+0], du*Bv[4*q+0]);
        h[4*q+1] = fmaf(p[4*q+1], h[4*q+1], du*Bv[4*q+1]);
        h[4*q+2] = fmaf(p[4*q+2], h[4*q+2], du*Bv[4*q+2]);
        h[4*q+3] = fmaf(p[4*q+3], h[4*q+3], du*Bv[4*q+3]);
        y0 = fmaf(h[4*q+0], Cv[4*q+0], y0);
        y1 = fmaf(h[4*q+1], Cv[4*q+1], y1);
        y2 = fmaf(h[4*q+2], Cv[4*q+2], y2);
        y3 = fmaf(h[4*q+3], Cv[4*q+3], y3);
      }
      float y = fmaf(u, Dd, (y0+y1)+(y2+y3));
      float z = bf2f(xz[row*1024 + 512 + d]);
      ysb[row*DINNER + d] = f2bf(y * siluf_(z));
    }
  } else {
    #pragma unroll 4
    for (int t=0;t<CHLEN;t++) {
      size_t row = row0 + t;
      float dlt, u;
      unpack_(pair[row*DINNER + d], dlt, u);
      float du = dlt*u;
      const float4* q4 = (const float4*)(dbl + row*48 + DTRANK);
      float4 v0 = q4[0], v1 = q4[1], v2 = q4[2], v3 = q4[3];
      float4 c0 = q4[4], c1 = q4[5], c2 = q4[6], c3 = q4[7];
      float Bv[16] = {v0.x,v0.y,v0.z,v0.w, v1.x,v1.y,v1.z,v1.w,
                      v2.x,v2.y,v2.z,v2.w, v3.x,v3.y,v3.z,v3.w};
      float Cv[16] = {c0.x,c0.y,c0.z,c0.w, c1.x,c1.y,c1.z,c1.w,
                      c2.x,c2.y,c2.z,c2.w, c3.x,c3.y,c3.z,c3.w};
      float y0=0.f, y1=0.f, y2=0.f, y3=0.f;
      #pragma unroll
      for (int q=0;q<4;q++) {
        float dA0 = __expf(dlt*A[4*q+0]);
        float dA1 = __expf(dlt*A[4*q+1]);
        float dA2 = __expf(dlt*A[4*q+2]);
        float dA3 = __expf(dlt*A[4*q+3]);
        h[4*q+0] = fmaf(dA0, h[4*q+0], du*Bv[4*q+0]);
        h[4*q+1] = fmaf(dA1, h[4*q+1], du*Bv[4*q+1]);
        h[4*q+2] = fmaf(dA2, h[4*q+2], du*Bv[4*q+2]);
        h[4*q+3] = fmaf(dA3, h[4*q+3], du*Bv[4*q+3]);
        y0 = fmaf(h[4*q+0], Cv[4*q+0], y0);
        y1 = fmaf(h[4*q+1], Cv[4*q+1], y1);
        y2 = fmaf(h[4*q+2], Cv[4*q+2], y2);
        y3 = fmaf(h[4*q+3], Cv[4*q+3], y3);
      }
      float y = fmaf(u, Dd, (y0+y1)+(y2+y3));
      float z = bf2f(xz[row*1024 + 512 + d]);
      ysb[row*DINNER + d] = f2bf(y * siluf_(z));
    }
  }
}

// partial pool over bf16 residual
__global__ void pool1_k(const ushort_t* __restrict__ h, float* __restrict__ part)
{
  int b = blockIdx.x, seg = blockIdx.y, d = threadIdx.x;
  float s = 0.f;
  size_t base = ((size_t)b*SEQL + seg*64)*DMODEL + d;
  for (int l=0;l<64;l++) s += bf2f(h[base + (size_t)l*DMODEL]);
  part[(b*32+seg)*DMODEL + d] = s;
}

// fused pool2 + decoder + softmax (one block, 1024 threads)
__global__ __launch_bounds__(1024) void pooldec_k(
    const float* __restrict__ part, const float* __restrict__ dw,
    const float* __restrict__ db, float* __restrict__ out)
{
  __shared__ float pooled[1024];
  __shared__ float lg[40];
  int t = threadIdx.x;
  int b = t >> 8, d = t & 255;
  float s = 0.f;
  for (int g=0; g<32; g++) s += part[(b*32+g)*DMODEL + d];
  pooled[b*DMODEL + d] = s * (1.f/SEQL);
  __syncthreads();
  if (t < 40) {
    int bb = t/10, o = t%10;
    float acc = db[o];
    const float* pv = pooled + bb*DMODEL;
    const float* wv = dw + o*DMODEL;
    for (int k=0;k<DMODEL;k++) acc = fmaf(pv[k], wv[k], acc);
    lg[t] = acc;
  }
  __syncthreads();
  if (t < 4) {
    float mx = -1e30f;
    for (int o=0;o<10;o++) mx = fmaxf(mx, lg[t*10+o]);
    float e[10]; float ss = 0.f;
    for (int o=0;o<10;o++) { e[o] = __expf(lg[t*10+o]-mx); ss += e[o]; }
    float inv = 1.f/ss;
    for (int o=0;o<10;o++) out[t*10+o] = e[o]*inv;
  }
}

extern "C" void kernel_launch(void* const* d_in, const int* in_sizes, int n_in,
                              void* d_out, int out_size, void* d_ws, size_t ws_size,
                              hipStream_t stream)
{
  const float* x      = (const float*)d_in[0];
  const float* enc_w  = (const float*)d_in[1];
  const float* enc_b  = (const float*)d_in[2];
  const float* ln_w   = (const float*)d_in[3];
  const float* ln_b   = (const float*)d_in[4];
  const float* inw    = (const float*)d_in[5];
  const float* cw     = (const float*)d_in[6];
  const float* cb     = (const float*)d_in[7];
  const float* xw     = (const float*)d_in[8];
  const float* dtw    = (const float*)d_in[9];
  const float* dtb    = (const float*)d_in[10];
  const float* A_log  = (const float*)d_in[11];
  const float* Dp     = (const float*)d_in[12];
  const float* ow     = (const float*)d_in[13];
  const float* dec_w  = (const float*)d_in[14];
  const float* dec_b  = (const float*)d_in[15];
  float* out = (float*)d_out;

  float* f = (float*)d_ws;
  float* b_dbl  = f; f += 393216;
  float* b_S    = f; f += 262144;
  float* b_part = f; f += 8192;
  unsigned int* b_pair = (unsigned int*)f; f += 4194304;
  ushort_t* u = (ushort_t*)f;
  ushort_t* hb    = u; u += 2097152;
  ushort_t* b_Hl  = u; u += 4194304;
  ushort_t* b_Hi  = u; u += 4194304;
  ushort_t* xb    = u; u += 1048576;
  ushort_t* encwb = u; u += 32768;
  ushort_t* inwb  = u; u += 524288;
  ushort_t* xwb   = u; u += 49152;
  ushort_t* owb   = u; u += 262144;
  ushort_t* lnb   = u; u += 2097152;
  ushort_t* xib   = u; u += 4194304;
  ushort_t* xzb   = u; u += 8388608;
  ushort_t* ysb   = u; u += 4194304;

  cast_all_k<<<1872, 256, 0, stream>>>(x, enc_w, inw, xw, ow,
                                       xb, encwb, inwb, xwb, owb);

  bgemm64<EPI_BIAS_BF><<<dim3(BLROWS/64, 2), 256, 0, stream>>>(
      xb, encwb, enc_b, nullptr, hb, BLROWS, DMODEL, 128);

  for (int i=0;i<2;i++) {
    const float* cwi = cw + i*DINNER*4;
    const float* cbi = cb + i*DINNER;
    const float* dtwi = dtw + (size_t)i*DINNER*16;
    const float* dtbi = dtb + i*DINNER;
    const float* Ai = A_log + (size_t)i*DINNER*16;
    ln_k<<<BLROWS/4, 256, 0, stream>>>(hb, ln_w + i*DMODEL, ln_b + i*DMODEL, lnb);
    bgemm128<EPI_XZ><<<dim3(BLROWS/128, 8), 256, 0, stream>>>(
        lnb, inwb + (size_t)i*262144, nullptr, nullptr, xzb, BLROWS, 1024, DMODEL);
    conv_silu_k<<<(BLROWS*DINNER/4)/256, 256, 0, stream>>>(xzb, cwi, cbi, xib);
    bgemm64<EPI_NONE><<<dim3(BLROWS/64, 1), 256, 0, stream>>>(
        xib, xwb + (size_t)i*24576, nullptr, nullptr, b_dbl, BLROWS, 48, DINNER);
    delta_k<<<BLROWS/8, 256, 0, stream>>>(b_dbl, dtwi, dtbi, xib, b_pair);
    scan1_k<<<BATCH*NCHUNK*2, 256, 0, stream>>>(
        b_pair, b_dbl, Ai, b_S, b_Hl);
    scomb_k<<<256, 128, 0, stream>>>(b_S, b_Hl, b_Hi, Ai);
    scan2_k<<<BATCH*NCHUNK*2, 256, 0, stream>>>(
        b_pair, b_dbl, Ai, b_Hi, Dp + i*DINNER, xzb, ysb);
    bgemm64<EPI_GELU_ADD_BF><<<dim3(BLROWS/64, 2), 256, 0, stream>>>(
        ysb, owb + (size_t)i*131072, nullptr, hb, hb, BLROWS, DMODEL, DINNER);
  }
  pool1_k<<<dim3(BATCH,32), 256, 0, stream>>>(hb, b_part);
  pooldec_k<<<1, 1024, 0, stream>>>(b_part, dec_w, dec_b, out);
}